// Round 8
// baseline (364.646 us; speedup 1.0000x reference)
//
#include <hip/hip_runtime.h>

#define N_PIX 1024

typedef __attribute__((ext_vector_type(8))) short bf16x8;
typedef __attribute__((ext_vector_type(4))) float f32x4;

__device__ inline ushort f2bf(float f) {
    union { float f; unsigned u; } v; v.f = f;
    unsigned u = v.u;
    return (ushort)((u + 0x7FFF + ((u >> 16) & 1)) >> 16);
}
__device__ inline float bf2f(ushort h) {
    union { unsigned u; float f; } v; v.u = ((unsigned)h) << 16; return v.f;
}

// ---------------------------------------------------------------------------
__global__ __launch_bounds__(256) void zero_kernel(float* __restrict__ p, int n)
{
    int i = blockIdx.x * 256 + threadIdx.x;
    if (i < n) p[i] = 0.f;
}

// ---------------------------------------------------------------------------
// Expand quaternion weight w[4][Cout][Cin] -> Hamilton matrix Wx[4Cout][4Cin] bf16
// ---------------------------------------------------------------------------
__global__ __launch_bounds__(256) void wexpand_kernel(
    const float* __restrict__ w, ushort* __restrict__ wx, int Cout, int Cin)
{
    int idx = blockIdx.x * 256 + threadIdx.x;
    int K = 4 * Cin;
    if (idx >= 4 * Cout * K) return;
    int m = idx / K, k = idx - m * K;
    int co = m >> 2, c = m & 3, ci = k >> 2, cp = k & 3;
    const int   CT[4][4] = {{0,1,2,3},{1,0,3,2},{2,3,0,1},{3,2,1,0}};
    const float ST[4][4] = {{1.f,-1.f,-1.f,-1.f},{1.f,1.f,1.f,-1.f},
                            {1.f,-1.f,1.f,1.f},{1.f,1.f,-1.f,1.f}};
    float val = ST[c][cp] * w[(size_t)CT[c][cp] * Cout * Cin + (size_t)co * Cin + ci];
    wx[idx] = f2bf(val);
}

// ---------------------------------------------------------------------------
// Pack fp32 activations [b][K][1024] -> bf16 [4096][K] (pixel-major), no BN.
// ---------------------------------------------------------------------------
__global__ __launch_bounds__(256) void pack_kernel(
    const float* __restrict__ src, int sbs, ushort* __restrict__ xp, int K)
{
    __shared__ float t[32][257];
    const int k0 = blockIdx.x * 32;
    const int P0 = blockIdx.y * 256;
    const int b = P0 >> 10, p0 = P0 & 1023;
    const float* s = src + (size_t)b * sbs + (size_t)k0 * N_PIX + p0;
#pragma unroll
    for (int i = 0; i < 32; i++)
        t[i][threadIdx.x] = s[i * N_PIX + threadIdx.x];
    __syncthreads();
#pragma unroll
    for (int j = 0; j < 32; j++) {
        int flat = j * 256 + threadIdx.x;
        int kk = flat & 31, p = flat >> 5;
        xp[(size_t)(P0 + p) * K + k0 + kk] = f2bf(t[kk][p]);
    }
}

// ---------------------------------------------------------------------------
// BN-apply + pack fused: reads raw conv out [4][M][1024], computes BN affine
// from raw sums, applies (+relu), writes bf16 [4096][*] pixel-major.
// k<ksplit -> dst0[p*ld0+k] ; else dst1[p*ld1+k].
// ---------------------------------------------------------------------------
__global__ __launch_bounds__(256) void applypack_kernel(
    const float* __restrict__ y, int M,
    const float* __restrict__ sraw,
    const float* __restrict__ g, const float* __restrict__ bta,
    ushort* __restrict__ dst0, int ld0,
    ushort* __restrict__ dst1, int ld1, int ksplit, int relu)
{
    __shared__ float t[32][257];
    __shared__ float gs[32], bs[32];
    const int k0 = blockIdx.x * 32;
    const int P0 = blockIdx.y * 256;
    const int b = P0 >> 10, p0 = P0 & 1023;
    if (threadIdx.x < 32) {
        int k = k0 + threadIdx.x;
        float mean = sraw[k * 2] * (1.f / 4096.f);
        float var  = sraw[k * 2 + 1] * (1.f / 4096.f) - mean * mean;
        float rs = rsqrtf(var + 1e-5f);
        float gg = g[k] * rs;
        gs[threadIdx.x] = gg;
        bs[threadIdx.x] = bta[k] - mean * gg;
    }
    __syncthreads();
    const float* s = y + (size_t)b * M * N_PIX + (size_t)k0 * N_PIX + p0;
#pragma unroll
    for (int i = 0; i < 32; i++) {
        float v = s[i * N_PIX + threadIdx.x] * gs[i] + bs[i];
        if (relu) v = fmaxf(v, 0.f);
        t[i][threadIdx.x] = v;
    }
    __syncthreads();
#pragma unroll
    for (int j = 0; j < 32; j++) {
        int flat = j * 256 + threadIdx.x;
        int kk = flat & 31, p = flat >> 5;
        int k = k0 + kk;
        ushort h = f2bf(t[kk][p]);
        if (k < ksplit) dst0[(size_t)(P0 + p) * ld0 + k] = h;
        else            dst1[(size_t)(P0 + p) * ld1 + k] = h;
    }
}

// ---------------------------------------------------------------------------
// Final BN apply from raw sums, fp32 channel-major out (+relu).
// ---------------------------------------------------------------------------
__global__ __launch_bounds__(256) void iqbn_apply2_kernel(
    const float* __restrict__ x, float* __restrict__ y,
    const float* __restrict__ sraw,
    const float* __restrict__ g, const float* __restrict__ bta, int relu)
{
    int cq = blockIdx.x & 511, b = blockIdx.x >> 9;
    float mean = sraw[cq * 2] * (1.f / 4096.f);
    float var  = sraw[cq * 2 + 1] * (1.f / 4096.f) - mean * mean;
    float rs = rsqrtf(var + 1e-5f);
    float ga = g[cq] * rs;
    float bb = bta[cq] - mean * ga;
    const float4* xp = (const float4*)(x + ((size_t)b * 512 + cq) * N_PIX);
    float4*       yp = (float4*)(y + ((size_t)b * 512 + cq) * N_PIX);
    float4 v = xp[threadIdx.x];
    v.x = v.x * ga + bb; v.y = v.y * ga + bb; v.z = v.z * ga + bb; v.w = v.w * ga + bb;
    if (relu) {
        v.x = fmaxf(v.x, 0.f); v.y = fmaxf(v.y, 0.f);
        v.z = fmaxf(v.z, 0.f); v.w = fmaxf(v.w, 0.f);
    }
    yp[threadIdx.x] = v;
}

// ---------------------------------------------------------------------------
// bf16 MFMA GEMM v2: D[M][4096] = Wx[M][K] * Xp^T, 2-phase pipelined,
// double-buffered LDS, fused per-row BN stats (atomicAdd to sraw).
// Tile 64x64, BK=64, grid (M/64, 64), 256 threads (2x2 waves, 32x32 each).
// ---------------------------------------------------------------------------
__global__ __launch_bounds__(256) void qgemm2_kernel(
    const ushort* __restrict__ xp,
    const ushort* __restrict__ wx,
    const float* __restrict__ bias,
    float* __restrict__ y,          // [4][M][1024]
    float* __restrict__ sraw,       // [M][2] or null
    int M, int K)
{
    __shared__ ushort As[2][8 * 64 * 8];   // [buf][(k8*64+row)*8]
    __shared__ ushort Bs[2][8 * 64 * 8];
    const int tid = threadIdx.x;
    const int m0 = blockIdx.x * 64;
    const int n0 = blockIdx.y * 64;
    const int w = tid >> 6, l = tid & 63;
    const int wm = w >> 1, wn = w & 1;
    const int lr = l & 15, lkb = l >> 4;
    const int srow = tid >> 2, sk8 = tid & 3;   // staging: 4 lanes/row, 64B coalesced

    const ushort* ga = wx + (size_t)(m0 + srow) * K + sk8 * 8;
    const ushort* gb = xp + (size_t)(n0 + srow) * K + sk8 * 8;

    int4 ra0, ra1, rb0, rb1;
#define LOADT(T) { int ko = (T) << 6; \
    ra0 = *(const int4*)(ga + ko);      ra1 = *(const int4*)(ga + ko + 32); \
    rb0 = *(const int4*)(gb + ko);      rb1 = *(const int4*)(gb + ko + 32); }
#define WRITET(BUF) { \
    *(int4*)&As[BUF][((sk8    ) * 64 + srow) * 8] = ra0; \
    *(int4*)&As[BUF][((sk8 + 4) * 64 + srow) * 8] = ra1; \
    *(int4*)&Bs[BUF][((sk8    ) * 64 + srow) * 8] = rb0; \
    *(int4*)&Bs[BUF][((sk8 + 4) * 64 + srow) * 8] = rb1; }

    const f32x4 z = {0.f, 0.f, 0.f, 0.f};
    f32x4 acc[2][2] = {{z, z}, {z, z}};
    const int nt = K >> 6;

    LOADT(0);
    WRITET(0);
    __syncthreads();

    for (int t = 0; t < nt; ++t) {
        if (t + 1 < nt) LOADT(t + 1);           // issue early: hides under MFMA
        const int bsel = t & 1;
#pragma unroll
        for (int kk = 0; kk < 2; kk++) {
            bf16x8 af[2], bf[2];
#pragma unroll
            for (int mi = 0; mi < 2; mi++)
                af[mi] = *(const bf16x8*)&As[bsel][((kk * 4 + lkb) * 64 + wm * 32 + mi * 16 + lr) * 8];
#pragma unroll
            for (int ni = 0; ni < 2; ni++)
                bf[ni] = *(const bf16x8*)&Bs[bsel][((kk * 4 + lkb) * 64 + wn * 32 + ni * 16 + lr) * 8];
#pragma unroll
            for (int mi = 0; mi < 2; mi++)
#pragma unroll
                for (int ni = 0; ni < 2; ni++)
                    acc[mi][ni] = __builtin_amdgcn_mfma_f32_16x16x32_bf16(
                        af[mi], bf[ni], acc[mi][ni], 0, 0, 0);
        }
        __syncthreads();
        if (t + 1 < nt) WRITET((t + 1) & 1);    // vmcnt wait lands here, post-MFMA
        __syncthreads();
    }
#undef LOADT
#undef WRITET

    // bias into acc first (stats must include bias)
    if (bias) {
#pragma unroll
        for (int mi = 0; mi < 2; mi++)
#pragma unroll
            for (int r = 0; r < 4; r++) {
                float bv = bias[m0 + wm * 32 + mi * 16 + lkb * 4 + r];
#pragma unroll
                for (int ni = 0; ni < 2; ni++) acc[mi][ni][r] += bv;
            }
    }

    // store: D col = lane&15, row = (lane>>4)*4 + r  [m89-verified]
#pragma unroll
    for (int mi = 0; mi < 2; mi++) {
        int mrow = m0 + wm * 32 + mi * 16 + lkb * 4;
#pragma unroll
        for (int ni = 0; ni < 2; ni++) {
            int col = n0 + wn * 32 + ni * 16 + lr;
            int bb = col >> 10, p = col & 1023;
            float* yb = y + (size_t)bb * M * N_PIX + (size_t)mrow * N_PIX + p;
#pragma unroll
            for (int r = 0; r < 4; r++) yb[(size_t)r * N_PIX] = acc[mi][ni][r];
        }
    }

    // fused BN stats: per-row sum / sumsq over this block's 64 cols
    if (sraw) {
#pragma unroll
        for (int mi = 0; mi < 2; mi++) {
#pragma unroll
            for (int r = 0; r < 4; r++) {
                float a0 = acc[mi][0][r], a1 = acc[mi][1][r];
                float sv = a0 + a1;
                float s2 = a0 * a0 + a1 * a1;
#pragma unroll
                for (int o = 1; o < 16; o <<= 1) {
                    sv += __shfl_xor(sv, o);
                    s2 += __shfl_xor(s2, o);
                }
                if (lr == 0) {
                    int row = m0 + wm * 32 + mi * 16 + lkb * 4 + r;
                    atomicAdd(&sraw[row * 2], sv);
                    atomicAdd(&sraw[row * 2 + 1], s2);
                }
            }
        }
    }
}

// ---------------------------------------------------------------------------
// MFMA flash attention — UNCHANGED from R5 (precision-frozen).
// ---------------------------------------------------------------------------
__global__ __launch_bounds__(256) void qattn_kernel(
    const float* __restrict__ qkv, float* __restrict__ o)
{
    __shared__ __attribute__((aligned(16))) char smem[24576];
    const int tid = threadIdx.x;
    const int grp = blockIdx.x;
    const int qc = grp & 3, hd = (grp >> 2) & 3, b = grp >> 4;
    const int n0 = blockIdx.y << 7;
    const int w = tid >> 6, lid = tid & 63;
    const int col = lid & 15, g = lid >> 4;
    const int swz = (col & 7) << 4;

    const float* gq = qkv + ((size_t)(b * 192 + hd * 48) * 4 + qc) * N_PIX;

    bf16x8 qf[2];
#pragma unroll
    for (int ns = 0; ns < 2; ns++) {
        int n = n0 + w * 32 + ns * 16 + col;
        const float* qg = gq + (size_t)((g & 1) * 8) * 4096 + n;
        union { bf16x8 v; ushort u[8]; } qq;
#pragma unroll
        for (int j = 0; j < 8; j++) {
            float qv = qg[(size_t)j * 4096] * 0.25f;
            ushort h = f2bf(qv);
            qq.u[j] = (g >= 2) ? f2bf(qv - bf2f(h)) : h;
        }
        qf[ns] = qq.v;
    }

    const f32x4 z = {0.f, 0.f, 0.f, 0.f};
    f32x4 O[2] = {z, z};
    float M[2] = {-1e30f, -1e30f}, L[2] = {0.f, 0.f};

    const int ml = tid & 63;
    const int d4 = (tid >> 6) << 2;

    for (int t = 0; t < 16; t++) {
        const int m0 = t << 6;
        __syncthreads();
        {
            const float* kg = gq + (size_t)(16 + d4) * 4096 + m0 + ml;
            const float* vg = gq + (size_t)(32 + d4) * 4096 + m0 + ml;
            float kv[4], vv[4];
#pragma unroll
            for (int i = 0; i < 4; i++) {
                kv[i] = kg[(size_t)i * 4096];
                vv[i] = vg[(size_t)i * 4096];
            }
            ushort kh[4], kl[4];
#pragma unroll
            for (int i = 0; i < 4; i++) {
                kh[i] = f2bf(kv[i]);
                kl[i] = f2bf(kv[i] - bf2f(kh[i]));
            }
            int sw = (ml & 7) << 4;
            int kbh = (ml * 64 + d4 * 2) ^ sw;
            int kbl = (ml * 64 + 32 + d4 * 2) ^ sw;
            *(uint2*)(smem + kbh) =
                make_uint2((uint)kh[0] | ((uint)kh[1] << 16), (uint)kh[2] | ((uint)kh[3] << 16));
            *(uint2*)(smem + kbl) =
                make_uint2((uint)kl[0] | ((uint)kl[1] << 16), (uint)kl[2] | ((uint)kl[3] << 16));
#pragma unroll
            for (int i = 0; i < 4; i++) {
                int d = d4 + i;
                ushort vh = f2bf(vv[i]);
                ushort vl = f2bf(vv[i] - bf2f(vh));
                int vb = (d * 128 + ml * 2) ^ ((d & 7) << 4);
                *(ushort*)(smem + 4096 + vb) = vh;
                *(ushort*)(smem + 6144 + vb) = vl;
            }
        }
        __syncthreads();

        f32x4 s[2][4];
#pragma unroll
        for (int ms = 0; ms < 4; ms++) {
            int rowb = (ms * 16 + col) * 64;
            bf16x8 a1 = *(const bf16x8*)(smem + ((rowb + g * 16) ^ swz));
            bf16x8 a2 = *(const bf16x8*)(smem + ((rowb + ((g ^ 2) * 16)) ^ swz));
#pragma unroll
            for (int ns = 0; ns < 2; ns++) {
                f32x4 c = __builtin_amdgcn_mfma_f32_16x16x32_bf16(a1, qf[ns], z, 0, 0, 0);
                s[ns][ms] = __builtin_amdgcn_mfma_f32_16x16x32_bf16(a2, qf[ns], c, 0, 0, 0);
            }
        }

#pragma unroll
        for (int ns = 0; ns < 2; ns++) {
            float tmax = s[ns][0][0];
#pragma unroll
            for (int ms = 0; ms < 4; ms++)
#pragma unroll
                for (int r = 0; r < 4; r++) tmax = fmaxf(tmax, s[ns][ms][r]);
            tmax = fmaxf(tmax, __shfl_xor(tmax, 16));
            tmax = fmaxf(tmax, __shfl_xor(tmax, 32));
            float Mn = fmaxf(M[ns], tmax);
            float rs = __expf(M[ns] - Mn);
            M[ns] = Mn;
            float psum = 0.f;
#pragma unroll
            for (int ms = 0; ms < 4; ms++) {
                f32x4 e;
#pragma unroll
                for (int r = 0; r < 4; r++) {
                    e[r] = __expf(s[ns][ms][r] - Mn);
                    psum += e[r];
                }
                s[ns][ms] = e;
            }
            psum += __shfl_xor(psum, 16);
            psum += __shfl_xor(psum, 32);
            L[ns] = L[ns] * rs + psum;
#pragma unroll
            for (int r = 0; r < 4; r++)
                O[ns][r] *= __shfl(rs, g * 4 + r);
            int nl = ns * 16 + col;
#pragma unroll
            for (int ms = 0; ms < 4; ms++) {
                uint plo = (uint)f2bf(s[ns][ms][0]) | ((uint)f2bf(s[ns][ms][1]) << 16);
                uint phi = (uint)f2bf(s[ns][ms][2]) | ((uint)f2bf(s[ns][ms][3]) << 16);
                int pb = (8192 + w * 4096 + nl * 128 + ms * 32 + g * 8) ^ swz;
                *(uint2*)(smem + pb) = make_uint2(plo, phi);
            }
        }
        __builtin_amdgcn_sched_barrier(0);

#pragma unroll
        for (int s2 = 0; s2 < 2; s2++) {
            int mb = s2 * 64 + g * 16;
            int vb = (col * 128 + mb) ^ swz;
            bf16x8 bvh = *(const bf16x8*)(smem + 4096 + vb);
            bf16x8 bvl = *(const bf16x8*)(smem + 6144 + vb);
#pragma unroll
            for (int ns = 0; ns < 2; ns++) {
                int nl = ns * 16 + col;
                bf16x8 ap = *(const bf16x8*)(smem + ((8192 + w * 4096 + nl * 128 + mb) ^ swz));
                O[ns] = __builtin_amdgcn_mfma_f32_16x16x32_bf16(ap, bvh, O[ns], 0, 0, 0);
                O[ns] = __builtin_amdgcn_mfma_f32_16x16x32_bf16(ap, bvl, O[ns], 0, 0, 0);
            }
        }
    }

#pragma unroll
    for (int ns = 0; ns < 2; ns++) {
        float invL = 1.f / L[ns];
#pragma unroll
        for (int r = 0; r < 4; r++)
            O[ns][r] *= __shfl(invL, g * 4 + r);
    }
    __syncthreads();
#pragma unroll
    for (int ns = 0; ns < 2; ns++) {
        int nloc = w * 32 + ns * 16 + g * 4;
        int ob = (8192 + col * 512 + nloc * 4) ^ swz;
        *(f32x4*)(smem + ob) = O[ns];
    }
    __syncthreads();
    {
        int d = tid >> 4, nb = (tid & 15) << 3;
        int b0 = (8192 + d * 512 + nb * 4) ^ ((d & 7) << 4);
        int b1 = (8192 + d * 512 + nb * 4 + 16) ^ ((d & 7) << 4);
        float4 o0 = *(const float4*)(smem + b0);
        float4 o1 = *(const float4*)(smem + b1);
        float* op = o + ((size_t)(b * 64 + hd * 16 + d) * 4 + qc) * N_PIX + n0 + nb;
        *(float4*)op = o0;
        *(float4*)(op + 4) = o1;
    }
}

// ---------------------------------------------------------------------------
// 3x3 grouped quaternion conv + residual add (unchanged).
// ---------------------------------------------------------------------------
__global__ __launch_bounds__(256) void pe_conv_kernel(
    const float* __restrict__ x,
    const float* __restrict__ w,
    const float* __restrict__ bias,
    float* __restrict__ y)
{
    const int bid = blockIdx.x;
    const int pt = bid & 3, co = (bid >> 2) & 63, b = bid >> 8;
    const int p = (pt << 8) + threadIdx.x;
    const int hh = p >> 5, ww = p & 31;
    const int g4 = (co >> 2) << 2;

    float a0 = bias[co * 4 + 0], a1 = bias[co * 4 + 1];
    float a2 = bias[co * 4 + 2], a3 = bias[co * 4 + 3];
    const float* xb = x + (size_t)b * 64 * 4096;
    const float* wb = w + co * 36;

#pragma unroll
    for (int dy = 0; dy < 3; dy++) {
        int yy = hh + dy - 1;
        if ((unsigned)yy >= 32u) continue;
#pragma unroll
        for (int dx = 0; dx < 3; dx++) {
            int xx = ww + dx - 1;
            if ((unsigned)xx >= 32u) continue;
            int sp = yy * 32 + xx;
#pragma unroll
            for (int cl = 0; cl < 4; cl++) {
                const float* xp = xb + (size_t)(g4 + cl) * 4096 + sp;
                float xr = xp[0], xi = xp[1024], xj = xp[2048], xk = xp[3072];
                const float* wp = wb + cl * 9 + dy * 3 + dx;
                float wr = wp[0], wi = wp[2304], wj2 = wp[4608], wk = wp[6912];
                a0 += xr * wr - xi * wi  - xj * wj2 - xk * wk;
                a1 += xr * wi + xi * wr  + xj * wk  - xk * wj2;
                a2 += xr * wj2 - xi * wk + xj * wr  + xk * wi;
                a3 += xr * wk + xi * wj2 - xj * wi  + xk * wr;
            }
        }
    }
    size_t ob = (size_t)b * 64 * 4096 + (size_t)co * 4096 + p;
    y[ob]        = x[ob]        + a0;
    y[ob + 1024] = x[ob + 1024] + a1;
    y[ob + 2048] = x[ob + 2048] + a2;
    y[ob + 3072] = x[ob + 3072] + a3;
}

// ---------------------------------------------------------------------------
extern "C" void kernel_launch(void* const* d_in, const int* in_sizes, int n_in,
                              void* d_out, int out_size, void* d_ws, size_t ws_size,
                              hipStream_t stream)
{
    const float* x      = (const float*)d_in[0];
    const float* cv1_w  = (const float*)d_in[1];
    const float* bn1_g  = (const float*)d_in[2];
    const float* bn1_b  = (const float*)d_in[3];
    const float* qkv_w  = (const float*)d_in[4];
    const float* qkv_b  = (const float*)d_in[5];
    const float* proj_w = (const float*)d_in[6];
    const float* proj_b = (const float*)d_in[7];
    const float* pe_w   = (const float*)d_in[8];
    const float* pe_b   = (const float*)d_in[9];
    const float* ang    = (const float*)d_in[10];
    const float* anb    = (const float*)d_in[11];
    const float* ffn1_w = (const float*)d_in[12];
    const float* fbn1_g = (const float*)d_in[13];
    const float* fbn1_b = (const float*)d_in[14];
    const float* ffn2_w = (const float*)d_in[15];
    const float* fbn2_g = (const float*)d_in[16];
    const float* fbn2_b = (const float*)d_in[17];
    const float* cv2_w  = (const float*)d_in[18];
    const float* bn2_g  = (const float*)d_in[19];
    const float* bn2_b  = (const float*)d_in[20];
    float* out = (float*)d_out;

    float* ws = (float*)d_ws;
    float*  qkvb  = ws;                         // [4][768][1024]  (bufB aliases)
    float*  bufA  = ws + 3145728;               // [4][256][1024] attn out
    float*  rawA  = ws + 4194304;               // [4][512][1024]
    float*  rawB  = ws + 6291456;               // [4][256][1024]
    float*  stats = ws + 7340032;               // 5 x 2048
    ushort* Wx    = (ushort*)(ws + 7350272);    // 512x512 bf16
    ushort* XpIn  = (ushort*)(ws + 7481344);    // 4096x512 (also XpF1, XpF2)
    ushort* XpA   = (ushort*)(ws + 8529920);    // 4096x256 (also XpP)
    ushort* XpCv2 = (ushort*)(ws + 9054208);    // 4096x512
    float*  bufB  = qkvb;                       // pe out, qkv dead after attn
    ushort* XpF1  = XpIn;
    ushort* XpF2  = XpIn;
    ushort* XpP   = XpA;

    float* st_cv1  = stats;
    float* st_proj = stats + 2048;
    float* st_ffn1 = stats + 4096;
    float* st_ffn2 = stats + 6144;
    float* st_cv2  = stats + 8192;

    const int S128 = 128 * 4096, S64 = 64 * 4096;

    zero_kernel<<<40, 256, 0, stream>>>(stats, 10240);

    // 1. cv1 (512x4096x512) -> rawA + stats; applypack -> XpA (a) / XpCv2[256:] (b)
    wexpand_kernel<<<1024, 256, 0, stream>>>(cv1_w, Wx, 128, 128);
    pack_kernel<<<dim3(16, 16), 256, 0, stream>>>(x, S128, XpIn, 512);
    qgemm2_kernel<<<dim3(8, 64), 256, 0, stream>>>(XpIn, Wx, nullptr, rawA, st_cv1, 512, 512);
    applypack_kernel<<<dim3(16, 16), 256, 0, stream>>>(rawA, 512, st_cv1, bn1_g, bn1_b,
                                                       XpA, 256, XpCv2, 512, 256, 1);

    // 2. qkv (768x4096x256) -> qkvb
    wexpand_kernel<<<768, 256, 0, stream>>>(qkv_w, Wx, 192, 64);
    qgemm2_kernel<<<dim3(12, 64), 256, 0, stream>>>(XpA, Wx, qkv_b, qkvb, nullptr, 768, 256);

    // 3. attention -> bufA
    qattn_kernel<<<dim3(64, 8), 256, 0, stream>>>(qkvb, bufA);

    // 4. pe conv + residual -> bufB ; pack -> XpP
    pe_conv_kernel<<<1024, 256, 0, stream>>>(bufA, pe_w, pe_b, bufB);
    pack_kernel<<<dim3(8, 16), 256, 0, stream>>>(bufB, S64, XpP, 256);

    // 5. proj (256x4096x256) -> rawB + stats; applypack -> XpF1
    wexpand_kernel<<<256, 256, 0, stream>>>(proj_w, Wx, 64, 64);
    qgemm2_kernel<<<dim3(4, 64), 256, 0, stream>>>(XpP, Wx, proj_b, rawB, st_proj, 256, 256);
    applypack_kernel<<<dim3(8, 16), 256, 0, stream>>>(rawB, 256, st_proj, ang, anb,
                                                      XpF1, 256, XpF1, 256, 1 << 20, 0);

    // 6. ffn1 (512x4096x256) -> rawA + stats; applypack(relu) -> XpF2
    wexpand_kernel<<<512, 256, 0, stream>>>(ffn1_w, Wx, 128, 64);
    qgemm2_kernel<<<dim3(8, 64), 256, 0, stream>>>(XpF1, Wx, nullptr, rawA, st_ffn1, 512, 256);
    applypack_kernel<<<dim3(16, 16), 256, 0, stream>>>(rawA, 512, st_ffn1, fbn1_g, fbn1_b,
                                                       XpF2, 512, XpF2, 512, 1 << 20, 1);

    // 7. ffn2 (256x4096x512) -> rawB + stats; applypack -> XpCv2[0:256] (free concat)
    wexpand_kernel<<<512, 256, 0, stream>>>(ffn2_w, Wx, 64, 128);
    qgemm2_kernel<<<dim3(4, 64), 256, 0, stream>>>(XpF2, Wx, nullptr, rawB, st_ffn2, 256, 512);
    applypack_kernel<<<dim3(8, 16), 256, 0, stream>>>(rawB, 256, st_ffn2, fbn2_g, fbn2_b,
                                                      XpCv2, 512, XpCv2, 512, 1 << 20, 0);

    // 8. cv2 (512x4096x512) -> rawA + stats; final apply -> out
    wexpand_kernel<<<1024, 256, 0, stream>>>(cv2_w, Wx, 128, 128);
    qgemm2_kernel<<<dim3(8, 64), 256, 0, stream>>>(XpCv2, Wx, nullptr, rawA, st_cv2, 512, 512);
    iqbn_apply2_kernel<<<2048, 256, 0, stream>>>(rawA, out, st_cv2, bn2_g, bn2_b, 1);
}